// Round 8
// baseline (175.894 us; speedup 1.0000x reference)
//
#include <hip/hip_runtime.h>
#include <hip/hip_bf16.h>

#define NN 6144
#define DLAT 512
#define SPLITK 4
#define KRANGE (NN / SPLITK)      // 1536
#define KSTEPS (KRANGE / 64)      // 24
#define NROWBLK (NN / 32)         // 192
#define NWG (NROWBLK * SPLITK)    // 768

typedef __attribute__((ext_vector_type(8))) short bf16x8;
typedef __attribute__((ext_vector_type(4))) float f32x4;

// Unnormalized kernel value, clamp folded into log domain:
//   clip(D^-a,1e-8,1e3) * e^(-D/12) = e^( clamp(-a*ln D, ln 1e-8, ln 1e3) - D/12 )
__device__ __forceinline__ float kerval(float pix, float piy, float piz, float sqi, float ahi,
                                        float4 pj, float sqj, float ahj) {
  float dot = fmaf(piz, pj.z, fmaf(piy, pj.y, pix * pj.x));
  float d2  = fmaf(-2.f, dot, sqi + sqj);
  float D   = sqrtf(fmaxf(d2, 1e-12f)) + 1e-6f;
  float a   = ahi + ahj;
  float tt  = -a * __logf(D);
  tt = fminf(fmaxf(tt, -18.420680743952367f), 6.907755278982137f);
  return __expf(fmaf(D, -1.f/12.f, tt));
}

// ---------------- prep: pack coords+alpha into float4 ----------------
__global__ __launch_bounds__(256) void prep_kernel(const float* __restrict__ coords,
                                                   const float* __restrict__ alpha,
                                                   float4* __restrict__ pre) {
  int j = blockIdx.x * 256 + threadIdx.x;
  if (j < NN) pre[j] = make_float4(coords[3*j], coords[3*j+1], coords[3*j+2], alpha[j]);
}

// ---------------- row sums -> inv (8 rows per block, compute-only) ----------------
__global__ __launch_bounds__(256) void rowinv_kernel(const float4* __restrict__ pre,
                                                     float* __restrict__ inv) {
  const int i0 = blockIdx.x * 8;
  const int t = threadIdx.x;
  const int lane = t & 63;
  const int w = t >> 6;
  float4 pi[8];
  float sqi[8], ah[8], s[8];
#pragma unroll
  for (int r = 0; r < 8; ++r) {
    pi[r] = pre[i0 + r];
    sqi[r] = fmaf(pi[r].z, pi[r].z, fmaf(pi[r].y, pi[r].y, pi[r].x*pi[r].x));
    ah[r] = 0.5f * pi[r].w;
    s[r] = 0.f;
  }
  for (int j = t; j < NN; j += 256) {
    float4 pj = pre[j];
    float sqj = fmaf(pj.z, pj.z, fmaf(pj.y, pj.y, pj.x*pj.x));
    float ajh = 0.5f * pj.w;
#pragma unroll
    for (int r = 0; r < 8; ++r) {
      float v = kerval(pi[r].x, pi[r].y, pi[r].z, sqi[r], ah[r], pj, sqj, ajh);
      if (j == i0 + r) v = 0.f;
      s[r] += v;
    }
  }
#pragma unroll
  for (int r = 0; r < 8; ++r)
#pragma unroll
    for (int off = 32; off > 0; off >>= 1) s[r] += __shfl_down(s[r], off);
  __shared__ float red[8][4];
  if (lane == 0) {
#pragma unroll
    for (int r = 0; r < 8; ++r) red[r][w] = s[r];
  }
  __syncthreads();
  if (t < 8) inv[i0 + t] = 1.f / (red[t][0] + red[t][1] + red[t][2] + red[t][3] + 1e-8f);
}

// ---------------- latent -> MFMA-fragment-ordered bf16 BT2 ----------------
// BT2[jt][colgrp][lane][8]: lane l holds latent[jt*32 + (l>>4)*8 + q][colgrp*16 + (l&15)]
__global__ __launch_bounds__(256) void btile_kernel(const float* __restrict__ latent,
                                                    __hip_bfloat16* __restrict__ BT2) {
  const int jt = blockIdx.x;                    // 0..191
  __shared__ __hip_bfloat16 tile[32][514];
  const int t = threadIdx.x;
#pragma unroll
  for (int s = 0; s < 16; ++s) {
    int idx = s*256 + t;
    int row = idx >> 7;
    int c4  = (idx & 127) * 4;
    float4 v = *(const float4*)&latent[(size_t)(jt*32 + row)*DLAT + c4];
    tile[row][c4+0] = __float2bfloat16(v.x);
    tile[row][c4+1] = __float2bfloat16(v.y);
    tile[row][c4+2] = __float2bfloat16(v.z);
    tile[row][c4+3] = __float2bfloat16(v.w);
  }
  __syncthreads();
  const int l = t & 63;
  const int w = t >> 6;
  const int lr = (l >> 4) * 8;
  const int lc = l & 15;
#pragma unroll
  for (int cg0 = 0; cg0 < 8; ++cg0) {
    const int cg = w*8 + cg0;
    __hip_bfloat16 h[8];
#pragma unroll
    for (int q = 0; q < 8; ++q) h[q] = tile[lr + q][cg*16 + lc];
    *(bf16x8*)(BT2 + ((size_t)(jt*32 + cg)*64 + l)*8) = *(const bf16x8*)h;
  }
}

// ---------------- fused: generate K tile -> fp32 K write + bf16 MFMA ----------------
// block = 32 rows x 512 cols, 4 waves (each 32x128), split-K=4 over j.
// Barrier discipline (HK T3/T4): raw s_barrier + lgkmcnt(0) ONLY — global K-stores
// (nontemporal) are never drained; all cross-wave deps (As, preJ) go through LDS.
// preJ is stored PERMUTED (swl involution) so A-gen reads are conflict-free;
// both the reg-stage source index and the read index use the same permutation.
__global__ __launch_bounds__(256, 3) void fused_kernel(const float4* __restrict__ pre,
                                                       const float* __restrict__ inv,
                                                       const __hip_bfloat16* __restrict__ BT2,
                                                       float* __restrict__ Kout,
                                                       float* __restrict__ parts) {
  __shared__ __align__(16) short As[2][8][32][8];   // [buf][granule][row][8 bf16]
  __shared__ __align__(16) float4 preJ[2][64];

  const int bx = blockIdx.x;
  const int wg = (bx & 7) * (NWG >> 3) + (bx >> 3);   // XCD-chunked: 2 XCDs share one z
  const int rowblk = wg % NROWBLK;
  const int z = wg / NROWBLK;
  const int rowBase = rowblk * 32;
  const int k0 = z * KRANGE;

  const int t = threadIdx.x;
  const int lane = t & 63;
  const int w = t >> 6;
  const int fr = lane & 15;
  const int fk = lane >> 4;

  // A-gen mapping: thread owns row r, j-granule jg (8 j's)
  const int r  = t >> 3;
  const int jg = t & 7;
  const int irow = rowBase + r;
  const float4 pi = pre[irow];
  const float sqi = fmaf(pi.z, pi.z, fmaf(pi.y, pi.y, pi.x*pi.x));
  const float ahi = 0.5f * pi.w;
  const float rinv = inv[irow];

  const int rk = rowBase - k0;
  const bool hasd = (unsigned)rk < (unsigned)KRANGE;   // block contains diagonal?
  const int dkt = rk >> 6;

  // bit-swap involution: preJ[x] holds pre[j0 + swl(x)]; A-gen reads preJ[q*8+jg]
  // = pre[j0 + jg*8 + q] (its j), and consecutive jg hit distinct bank-quads.
  const int swl = ((lane & 7) << 3) | (lane >> 3);

  // strength-reduced pointers
  const __hip_bfloat16* bbase = BT2 + ((size_t)(k0 >> 5) * 32 + w * 8) * 512 + lane * 8;
  float* kp = Kout + (size_t)irow * NN + k0 + jg * 8;

  f32x4 acc[2][8];
#pragma unroll
  for (int m = 0; m < 2; ++m)
#pragma unroll
    for (int n = 0; n < 8; ++n) acc[m][n] = (f32x4){0.f, 0.f, 0.f, 0.f};

  // prologue: stage preJ[0] (global->reg->LDS, permuted), full sync once
  if (w == 0) preJ[0][lane] = pre[k0 + swl];
  __syncthreads();

  for (int kt = 0; kt < KSTEPS; ++kt) {
    const int b = kt & 1;
    const int j0 = k0 + kt * 64;

    // issue BOTH B-subtile fragment loads early (L2 latency hides under A-gen VALU)
    bf16x8 b0[8], b1[8];
#pragma unroll
    for (int n = 0; n < 8; ++n) b0[n] = *(const bf16x8*)(bbase + n * 512);
#pragma unroll
    for (int n = 0; n < 8; ++n) b1[n] = *(const bf16x8*)(bbase + 16384 + n * 512);
    bbase += 32768;

    // stage next preJ into regs (wave 0), permuted source
    float4 pj_stage;
    if (w == 0 && kt + 1 < KSTEPS) pj_stage = pre[j0 + 64 + swl];

    // ---- A-gen: 8 elems/thread ----
    float kv[8];
#pragma unroll
    for (int q = 0; q < 8; ++q) {
      float4 pj = preJ[b][q*8 + jg];                   // holds pre[j0 + jg*8 + q]
      float sqj = fmaf(pj.z, pj.z, fmaf(pj.y, pj.y, pj.x*pj.x));
      kv[q] = kerval(pi.x, pi.y, pi.z, sqi, ahi, pj, sqj, 0.5f*pj.w) * rinv;
    }
    if (hasd && kt == dkt) {
#pragma unroll
      for (int q = 0; q < 8; ++q)
        if (j0 + jg*8 + q == irow) kv[q] = 0.f;
    }
    // fp32 K write: nontemporal, fire-and-forget, never drained
    {
      f32x4 v0 = {kv[0], kv[1], kv[2], kv[3]};
      f32x4 v1 = {kv[4], kv[5], kv[6], kv[7]};
      __builtin_nontemporal_store(v0, (f32x4*)kp);
      __builtin_nontemporal_store(v1, (f32x4*)(kp + 4));
    }
    kp += 64;
    {
      __hip_bfloat16 hb[8];
#pragma unroll
      for (int q = 0; q < 8; ++q) hb[q] = __float2bfloat16(kv[q]);
      *(bf16x8*)&As[b][jg][r][0] = *(const bf16x8*)hb;
    }
    if (w == 0 && kt + 1 < KSTEPS) preJ[b ^ 1][lane] = pj_stage;  // reg->LDS

    // barrier WITHOUT vmcnt drain: LDS deps only
    __builtin_amdgcn_sched_barrier(0);
    asm volatile("s_waitcnt lgkmcnt(0)" ::: "memory");
    __builtin_amdgcn_sched_barrier(0);
    __builtin_amdgcn_s_barrier();
    __builtin_amdgcn_sched_barrier(0);

    // ---- MFMA: 32 per wave per K-step ----
    __builtin_amdgcn_s_setprio(1);
    {
      bf16x8 av0 = *(const bf16x8*)&As[b][fk][fr][0];       // ks=0
      bf16x8 av1 = *(const bf16x8*)&As[b][fk][16 + fr][0];
#pragma unroll
      for (int n = 0; n < 8; ++n) {
        acc[0][n] = __builtin_amdgcn_mfma_f32_16x16x32_bf16(av0, b0[n], acc[0][n], 0, 0, 0);
        acc[1][n] = __builtin_amdgcn_mfma_f32_16x16x32_bf16(av1, b0[n], acc[1][n], 0, 0, 0);
      }
      av0 = *(const bf16x8*)&As[b][4 + fk][fr][0];          // ks=1
      av1 = *(const bf16x8*)&As[b][4 + fk][16 + fr][0];
#pragma unroll
      for (int n = 0; n < 8; ++n) {
        acc[0][n] = __builtin_amdgcn_mfma_f32_16x16x32_bf16(av0, b1[n], acc[0][n], 0, 0, 0);
        acc[1][n] = __builtin_amdgcn_mfma_f32_16x16x32_bf16(av1, b1[n], acc[1][n], 0, 0, 0);
      }
    }
    __builtin_amdgcn_s_setprio(0);
  }

  float* dst = parts + (size_t)z * NN * DLAT;
  const int colW = w * 128;
#pragma unroll
  for (int m = 0; m < 2; ++m)
#pragma unroll
    for (int n = 0; n < 8; ++n) {
      const int row0 = rowBase + m*16 + fk*4;
      const int c0   = colW + n*16 + fr;
#pragma unroll
      for (int i2 = 0; i2 < 4; ++i2)
        __builtin_nontemporal_store(acc[m][n][i2], &dst[(size_t)(row0 + i2)*DLAT + c0]);
    }
}

// ---------------- reduce split-K partials ----------------
__global__ __launch_bounds__(256) void reduce_kernel(const f32x4* __restrict__ parts,
                                                     f32x4* __restrict__ out, int S) {
  const size_t stride = (size_t)NN * DLAT / 4;
  for (size_t idx = (size_t)blockIdx.x * 256 + threadIdx.x; idx < stride;
       idx += (size_t)gridDim.x * 256) {
    f32x4 a = __builtin_nontemporal_load(&parts[idx]);
    for (int zz = 1; zz < S; ++zz) {
      f32x4 bv = __builtin_nontemporal_load(&parts[idx + (size_t)zz * stride]);
      a += bv;
    }
    __builtin_nontemporal_store(a, &out[idx]);
  }
}

// ---------------- fallback path (tiny ws) ----------------
__global__ __launch_bounds__(256) void buildk_kernel(const float* __restrict__ coords,
                                                     const float* __restrict__ alpha,
                                                     float* __restrict__ Kout) {
  const int i = blockIdx.x;
  const int t = threadIdx.x;
  float ci0 = coords[3*i], ci1 = coords[3*i+1], ci2 = coords[3*i+2], ai = alpha[i];
  const float sqi = ci0*ci0 + ci1*ci1 + ci2*ci2;
  float vals[24];
  float lsum = 0.f;
#pragma unroll
  for (int it = 0; it < 24; ++it) {
    const int j = t + it*256;
    float c0 = coords[3*j], c1 = coords[3*j+1], c2 = coords[3*j+2], aj = alpha[j];
    float sqj = c0*c0 + c1*c1 + c2*c2;
    float dot = ci0*c0 + ci1*c1 + ci2*c2;
    float d2 = sqi + sqj - 2.f*dot;
    float D = sqrtf(fmaxf(d2, 1e-12f)) + 1e-6f;
    float a = 0.5f*(ai + aj);
    float p = __expf(-a * __logf(D));
    p = fminf(fmaxf(p, 1e-8f), 1000.f);
    float kvv = p * __expf(D * (-1.f/12.f));
    if (j == i) kvv = 0.f;
    vals[it] = kvv;
    lsum += kvv;
  }
#pragma unroll
  for (int off = 32; off > 0; off >>= 1) lsum += __shfl_down(lsum, off);
  __shared__ float red[4];
  if ((t & 63) == 0) red[t >> 6] = lsum;
  __syncthreads();
  const float inv = 1.f / (red[0] + red[1] + red[2] + red[3] + 1e-8f);
  const size_t rowoff = (size_t)i * NN;
#pragma unroll
  for (int it = 0; it < 24; ++it) Kout[rowoff + t + it*256] = vals[it] * inv;
}

__global__ __launch_bounds__(256) void gemm_fallback(const float* __restrict__ Afp,
                                                     const float* __restrict__ Bfp,
                                                     float* __restrict__ out) {
  __shared__ __align__(16) short As[2][128][72];
  __shared__ __align__(16) short Bs[2][64][72];
  const int t = threadIdx.x;
  const int rowBase = blockIdx.x * 128;
  const int colBase = blockIdx.y * 64;
  const int lane = t & 63;
  const int w  = t >> 6;
  const int wr = w >> 1;
  const int wc = w & 1;
  const int fr = lane & 15;
  const int fk = lane >> 4;
  int4 ra[4], rb[2];
  auto load_regs = [&](int kt) {
#pragma unroll
    for (int s = 0; s < 4; ++s) {
      int c = t + s*256; int rr = c >> 3, q = c & 7;
      const float* src = Afp + (size_t)(rowBase + rr)*NN + kt*64 + q*8;
      float4 f0 = *(const float4*)src;
      float4 f1 = *(const float4*)(src + 4);
      __hip_bfloat16 h[8];
      h[0]=__float2bfloat16(f0.x); h[1]=__float2bfloat16(f0.y);
      h[2]=__float2bfloat16(f0.z); h[3]=__float2bfloat16(f0.w);
      h[4]=__float2bfloat16(f1.x); h[5]=__float2bfloat16(f1.y);
      h[6]=__float2bfloat16(f1.z); h[7]=__float2bfloat16(f1.w);
      ra[s] = *(const int4*)h;
    }
#pragma unroll
    for (int s = 0; s < 2; ++s) {
      int c = t + s*256; int rr = c >> 3, q = c & 7;
      const float* src = Bfp + (size_t)(kt*64 + q*8)*DLAT + colBase + rr;
      __hip_bfloat16 h[8];
#pragma unroll
      for (int i2 = 0; i2 < 8; ++i2) h[i2] = __float2bfloat16(src[(size_t)i2*DLAT]);
      rb[s] = *(const int4*)h;
    }
  };
  auto write_tiles = [&](int buf) {
#pragma unroll
    for (int s = 0; s < 4; ++s) {
      int c = t + s*256; int rr = c >> 3, q = c & 7;
      *(int4*)&As[buf][rr][q*8] = ra[s];
    }
#pragma unroll
    for (int s = 0; s < 2; ++s) {
      int c = t + s*256; int rr = c >> 3, q = c & 7;
      *(int4*)&Bs[buf][rr][q*8] = rb[s];
    }
  };
  f32x4 acc[4][2];
#pragma unroll
  for (int m = 0; m < 4; ++m)
#pragma unroll
    for (int n = 0; n < 2; ++n) acc[m][n] = (f32x4){0.f,0.f,0.f,0.f};
  auto compute = [&](int buf) {
#pragma unroll
    for (int ks = 0; ks < 2; ++ks) {
      bf16x8 av[4], bv[2];
#pragma unroll
      for (int m = 0; m < 4; ++m) av[m] = *(const bf16x8*)&As[buf][wr*64 + m*16 + fr][ks*32 + fk*8];
#pragma unroll
      for (int n = 0; n < 2; ++n) bv[n] = *(const bf16x8*)&Bs[buf][wc*32 + n*16 + fr][ks*32 + fk*8];
#pragma unroll
      for (int m = 0; m < 4; ++m)
#pragma unroll
        for (int n = 0; n < 2; ++n)
          acc[m][n] = __builtin_amdgcn_mfma_f32_16x16x32_bf16(av[m], bv[n], acc[m][n], 0, 0, 0);
    }
  };
  load_regs(0); write_tiles(0); __syncthreads();
  int buf = 0;
  for (int kt = 0; kt < 96; ++kt) {
    if (kt + 1 < 96) load_regs(kt + 1);
    compute(buf);
    if (kt + 1 < 96) write_tiles(buf ^ 1);
    __syncthreads();
    buf ^= 1;
  }
#pragma unroll
  for (int m = 0; m < 4; ++m)
#pragma unroll
    for (int n = 0; n < 2; ++n) {
      const int row0 = rowBase + wr*64 + m*16 + fk*4;
      const int c0   = colBase + wc*32 + n*16 + fr;
#pragma unroll
      for (int i2 = 0; i2 < 4; ++i2)
        out[(size_t)(row0 + i2)*DLAT + c0] = acc[m][n][i2];
    }
}

extern "C" void kernel_launch(void* const* d_in, const int* in_sizes, int n_in,
                              void* d_out, int out_size, void* d_ws, size_t ws_size,
                              hipStream_t stream) {
  const float* latent = (const float*)d_in[0];
  const float* coords = (const float*)d_in[1];
  const float* alpha  = (const float*)d_in[2];
  float* out  = (float*)d_out;                       // [6144,512]
  float* Kout = out + (size_t)NN * DLAT;             // [6144,6144]

  const size_t needB = (size_t)NN * DLAT * 2;        // BT2 bf16 (6.29 MB)
  const size_t needP = (size_t)NN * 16;              // pre float4
  const size_t needI = (size_t)NN * 4;               // inv
  const size_t needS = (size_t)SPLITK * NN * DLAT * 4;  // partials (50.3 MB)

  if (ws_size >= needB + needP + needI + needS) {
    __hip_bfloat16* BT2 = (__hip_bfloat16*)d_ws;
    float4* pre  = (float4*)((char*)d_ws + needB);
    float* inv   = (float*)((char*)d_ws + needB + needP);
    float* parts = (float*)((char*)d_ws + needB + needP + needI);

    prep_kernel<<<NN/256, 256, 0, stream>>>(coords, alpha, pre);
    btile_kernel<<<NN/32, 256, 0, stream>>>(latent, BT2);
    rowinv_kernel<<<NN/8, 256, 0, stream>>>(pre, inv);
    fused_kernel<<<NWG, 256, 0, stream>>>(pre, inv, BT2, Kout, parts);
    reduce_kernel<<<1024, 256, 0, stream>>>((const f32x4*)parts, (f32x4*)out, SPLITK);
  } else {
    buildk_kernel<<<NN, 256, 0, stream>>>(coords, alpha, Kout);
    gemm_fallback<<<dim3(NN/128, DLAT/64), 256, 0, stream>>>(Kout, latent, out);
  }
}

// Round 9
// 148.487 us; speedup vs baseline: 1.1846x; 1.1846x over previous
//
#include <hip/hip_runtime.h>
#include <hip/hip_bf16.h>

#define NN 6144
#define DLAT 512
#define SPLITK 4
#define KRANGE (NN / SPLITK)      // 1536
#define KSTEPS (KRANGE / 64)      // 24
#define NROWBLK (NN / 32)         // 192
#define NWG (NROWBLK * SPLITK)    // 768

typedef __attribute__((ext_vector_type(8))) short bf16x8;
typedef __attribute__((ext_vector_type(4))) float f32x4;

// Unnormalized kernel value, clamp folded into log domain:
//   clip(D^-a,1e-8,1e3) * e^(-D/12) = e^( clamp(-a*ln D, ln 1e-8, ln 1e3) - D/12 )
__device__ __forceinline__ float kerval(float pix, float piy, float piz, float sqi, float ahi,
                                        float4 pj, float sqj, float ahj) {
  float dot = fmaf(piz, pj.z, fmaf(piy, pj.y, pix * pj.x));
  float d2  = fmaf(-2.f, dot, sqi + sqj);
  float D   = sqrtf(fmaxf(d2, 1e-12f)) + 1e-6f;
  float a   = ahi + ahj;
  float tt  = -a * __logf(D);
  tt = fminf(fmaxf(tt, -18.420680743952367f), 6.907755278982137f);
  return __expf(fmaf(D, -1.f/12.f, tt));
}

// ---------------- prep: pack coords+alpha into float4 ----------------
__global__ __launch_bounds__(256) void prep_kernel(const float* __restrict__ coords,
                                                   const float* __restrict__ alpha,
                                                   float4* __restrict__ pre) {
  int j = blockIdx.x * 256 + threadIdx.x;
  if (j < NN) pre[j] = make_float4(coords[3*j], coords[3*j+1], coords[3*j+2], alpha[j]);
}

// ---------------- combined: btile (blocks 0..191) + rowinv (blocks 192..959) ----------------
// btile is memory-bound, rowinv pure-VALU: one launch lets them overlap on the machine.
__global__ __launch_bounds__(256) void aux_kernel(const float* __restrict__ latent,
                                                  const float4* __restrict__ pre,
                                                  __hip_bfloat16* __restrict__ BT2,
                                                  float* __restrict__ inv) {
  __shared__ __align__(16) char smem[32 * 514 * 2];
  const int t = threadIdx.x;

  if (blockIdx.x < NROWBLK) {
    // ---- btile: latent -> MFMA-fragment-ordered bf16 BT2 ----
    // BT2[jt][colgrp][lane][8]: lane l holds latent[jt*32 + (l>>4)*8 + q][colgrp*16 + (l&15)]
    __hip_bfloat16 (*tile)[514] = (__hip_bfloat16 (*)[514])smem;
    const int jt = blockIdx.x;
#pragma unroll
    for (int s = 0; s < 16; ++s) {
      int idx = s*256 + t;
      int row = idx >> 7;
      int c4  = (idx & 127) * 4;
      float4 v = *(const float4*)&latent[(size_t)(jt*32 + row)*DLAT + c4];
      tile[row][c4+0] = __float2bfloat16(v.x);
      tile[row][c4+1] = __float2bfloat16(v.y);
      tile[row][c4+2] = __float2bfloat16(v.z);
      tile[row][c4+3] = __float2bfloat16(v.w);
    }
    __syncthreads();
    const int l = t & 63;
    const int w = t >> 6;
    const int lr = (l >> 4) * 8;
    const int lc = l & 15;
#pragma unroll
    for (int cg0 = 0; cg0 < 8; ++cg0) {
      const int cg = w*8 + cg0;
      __hip_bfloat16 h[8];
#pragma unroll
      for (int q = 0; q < 8; ++q) h[q] = tile[lr + q][cg*16 + lc];
      *(bf16x8*)(BT2 + ((size_t)(jt*32 + cg)*64 + l)*8) = *(const bf16x8*)h;
    }
  } else {
    // ---- rowinv: row sums -> inv, 8 rows per block ----
    const int i0 = (blockIdx.x - NROWBLK) * 8;
    const int lane = t & 63;
    const int w = t >> 6;
    float4 pi[8];
    float sqi[8], ah[8], s[8];
#pragma unroll
    for (int r = 0; r < 8; ++r) {
      pi[r] = pre[i0 + r];
      sqi[r] = fmaf(pi[r].z, pi[r].z, fmaf(pi[r].y, pi[r].y, pi[r].x*pi[r].x));
      ah[r] = 0.5f * pi[r].w;
      s[r] = 0.f;
    }
    for (int j = t; j < NN; j += 256) {
      float4 pj = pre[j];
      float sqj = fmaf(pj.z, pj.z, fmaf(pj.y, pj.y, pj.x*pj.x));
      float ajh = 0.5f * pj.w;
#pragma unroll
      for (int r = 0; r < 8; ++r) {
        float v = kerval(pi[r].x, pi[r].y, pi[r].z, sqi[r], ah[r], pj, sqj, ajh);
        if (j == i0 + r) v = 0.f;
        s[r] += v;
      }
    }
#pragma unroll
    for (int r = 0; r < 8; ++r)
#pragma unroll
      for (int off = 32; off > 0; off >>= 1) s[r] += __shfl_down(s[r], off);
    float (*red)[4] = (float (*)[4])smem;
    if (lane == 0) {
#pragma unroll
      for (int r = 0; r < 8; ++r) red[r][w] = s[r];
    }
    __syncthreads();
    if (t < 8) inv[i0 + t] = 1.f / (red[t][0] + red[t][1] + red[t][2] + red[t][3] + 1e-8f);
  }
}

// ---------------- fused: generate K tile -> fp32 K write + bf16 MFMA ----------------
// block = 32 rows x 512 cols, 4 waves (each 32x128), split-K=4 over j.
// Barrier discipline (HK T3/T4): raw s_barrier + lgkmcnt(0) ONLY — plain cached
// K-stores stay in flight across barriers; all cross-wave deps (As, preJ) are LDS.
// preJ stored PERMUTED (swl involution), read back with the matching index.
__global__ __launch_bounds__(256, 3) void fused_kernel(const float4* __restrict__ pre,
                                                       const float* __restrict__ inv,
                                                       const __hip_bfloat16* __restrict__ BT2,
                                                       float* __restrict__ Kout,
                                                       float* __restrict__ parts) {
  __shared__ __align__(16) short As[2][8][32][8];   // [buf][granule][row][8 bf16]
  __shared__ __align__(16) float4 preJ[2][64];

  const int bx = blockIdx.x;
  const int wg = (bx & 7) * (NWG >> 3) + (bx >> 3);   // XCD-chunked: 2 XCDs share one z
  const int rowblk = wg % NROWBLK;
  const int z = wg / NROWBLK;
  const int rowBase = rowblk * 32;
  const int k0 = z * KRANGE;

  const int t = threadIdx.x;
  const int lane = t & 63;
  const int w = t >> 6;
  const int fr = lane & 15;
  const int fk = lane >> 4;

  // A-gen mapping: thread owns row r, j-granule jg (8 j's)
  const int r  = t >> 3;
  const int jg = t & 7;
  const int irow = rowBase + r;
  const float4 pi = pre[irow];
  const float sqi = fmaf(pi.z, pi.z, fmaf(pi.y, pi.y, pi.x*pi.x));
  const float ahi = 0.5f * pi.w;
  const float rinv = inv[irow];

  const int rk = rowBase - k0;
  const bool hasd = (unsigned)rk < (unsigned)KRANGE;   // block contains diagonal?
  const int dkt = rk >> 6;

  // bit-swap involution: preJ[x] holds pre[j0 + swl(x)]; A-gen reads preJ[q*8+jg]
  // = pre[j0 + jg*8 + q] — conflict-free broadcast per q.
  const int swl = ((lane & 7) << 3) | (lane >> 3);

  // strength-reduced pointers
  const __hip_bfloat16* bbase = BT2 + ((size_t)(k0 >> 5) * 32 + w * 8) * 512 + lane * 8;
  float* kp = Kout + (size_t)irow * NN + k0 + jg * 8;

  f32x4 acc[2][8];
#pragma unroll
  for (int m = 0; m < 2; ++m)
#pragma unroll
    for (int n = 0; n < 8; ++n) acc[m][n] = (f32x4){0.f, 0.f, 0.f, 0.f};

  // prologue: stage preJ[0] (global->reg->LDS, permuted), full sync once
  if (w == 0) preJ[0][lane] = pre[k0 + swl];
  __syncthreads();

  for (int kt = 0; kt < KSTEPS; ++kt) {
    const int b = kt & 1;
    const int j0 = k0 + kt * 64;

    // issue BOTH B-subtile fragment loads early (L2 latency hides under A-gen VALU)
    bf16x8 b0[8], b1[8];
#pragma unroll
    for (int n = 0; n < 8; ++n) b0[n] = *(const bf16x8*)(bbase + n * 512);
#pragma unroll
    for (int n = 0; n < 8; ++n) b1[n] = *(const bf16x8*)(bbase + 16384 + n * 512);
    bbase += 32768;

    // stage next preJ into regs (wave 0), permuted source
    float4 pj_stage;
    if (w == 0 && kt + 1 < KSTEPS) pj_stage = pre[j0 + 64 + swl];

    // ---- A-gen: 8 elems/thread ----
    float kv[8];
#pragma unroll
    for (int q = 0; q < 8; ++q) {
      float4 pj = preJ[b][q*8 + jg];                   // holds pre[j0 + jg*8 + q]
      float sqj = fmaf(pj.z, pj.z, fmaf(pj.y, pj.y, pj.x*pj.x));
      kv[q] = kerval(pi.x, pi.y, pi.z, sqi, ahi, pj, sqj, 0.5f*pj.w) * rinv;
    }
    if (hasd && kt == dkt) {
#pragma unroll
      for (int q = 0; q < 8; ++q)
        if (j0 + jg*8 + q == irow) kv[q] = 0.f;
    }
    // fp32 K write: plain cached stores (write-combine in L2), never drained in-loop
    {
      f32x4 v0 = {kv[0], kv[1], kv[2], kv[3]};
      f32x4 v1 = {kv[4], kv[5], kv[6], kv[7]};
      *(f32x4*)kp = v0;
      *(f32x4*)(kp + 4) = v1;
    }
    kp += 64;
    {
      __hip_bfloat16 hb[8];
#pragma unroll
      for (int q = 0; q < 8; ++q) hb[q] = __float2bfloat16(kv[q]);
      *(bf16x8*)&As[b][jg][r][0] = *(const bf16x8*)hb;
    }
    if (w == 0 && kt + 1 < KSTEPS) preJ[b ^ 1][lane] = pj_stage;  // reg->LDS

    // barrier WITHOUT vmcnt drain: LDS deps only
    __builtin_amdgcn_sched_barrier(0);
    asm volatile("s_waitcnt lgkmcnt(0)" ::: "memory");
    __builtin_amdgcn_sched_barrier(0);
    __builtin_amdgcn_s_barrier();
    __builtin_amdgcn_sched_barrier(0);

    // ---- MFMA: 32 per wave per K-step ----
    __builtin_amdgcn_s_setprio(1);
    {
      bf16x8 av0 = *(const bf16x8*)&As[b][fk][fr][0];       // ks=0
      bf16x8 av1 = *(const bf16x8*)&As[b][fk][16 + fr][0];
#pragma unroll
      for (int n = 0; n < 8; ++n) {
        acc[0][n] = __builtin_amdgcn_mfma_f32_16x16x32_bf16(av0, b0[n], acc[0][n], 0, 0, 0);
        acc[1][n] = __builtin_amdgcn_mfma_f32_16x16x32_bf16(av1, b0[n], acc[1][n], 0, 0, 0);
      }
      av0 = *(const bf16x8*)&As[b][4 + fk][fr][0];          // ks=1
      av1 = *(const bf16x8*)&As[b][4 + fk][16 + fr][0];
#pragma unroll
      for (int n = 0; n < 8; ++n) {
        acc[0][n] = __builtin_amdgcn_mfma_f32_16x16x32_bf16(av0, b1[n], acc[0][n], 0, 0, 0);
        acc[1][n] = __builtin_amdgcn_mfma_f32_16x16x32_bf16(av1, b1[n], acc[1][n], 0, 0, 0);
      }
    }
    __builtin_amdgcn_s_setprio(0);
  }

  float* dst = parts + (size_t)z * NN * DLAT;
  const int colW = w * 128;
#pragma unroll
  for (int m = 0; m < 2; ++m)
#pragma unroll
    for (int n = 0; n < 8; ++n) {
      const int row0 = rowBase + m*16 + fk*4;
      const int c0   = colW + n*16 + fr;
#pragma unroll
      for (int i2 = 0; i2 < 4; ++i2)
        dst[(size_t)(row0 + i2)*DLAT + c0] = acc[m][n][i2];
    }
}

// ---------------- reduce split-K partials ----------------
__global__ __launch_bounds__(256) void reduce_kernel(const f32x4* __restrict__ parts,
                                                     f32x4* __restrict__ out, int S) {
  const size_t stride = (size_t)NN * DLAT / 4;
  for (size_t idx = (size_t)blockIdx.x * 256 + threadIdx.x; idx < stride;
       idx += (size_t)gridDim.x * 256) {
    f32x4 a = parts[idx];
    for (int zz = 1; zz < S; ++zz) {
      f32x4 bv = parts[idx + (size_t)zz * stride];
      a += bv;
    }
    out[idx] = a;
  }
}

// ---------------- fallback path (tiny ws) ----------------
__global__ __launch_bounds__(256) void buildk_kernel(const float* __restrict__ coords,
                                                     const float* __restrict__ alpha,
                                                     float* __restrict__ Kout) {
  const int i = blockIdx.x;
  const int t = threadIdx.x;
  float ci0 = coords[3*i], ci1 = coords[3*i+1], ci2 = coords[3*i+2], ai = alpha[i];
  const float sqi = ci0*ci0 + ci1*ci1 + ci2*ci2;
  float vals[24];
  float lsum = 0.f;
#pragma unroll
  for (int it = 0; it < 24; ++it) {
    const int j = t + it*256;
    float c0 = coords[3*j], c1 = coords[3*j+1], c2 = coords[3*j+2], aj = alpha[j];
    float sqj = c0*c0 + c1*c1 + c2*c2;
    float dot = ci0*c0 + ci1*c1 + ci2*c2;
    float d2 = sqi + sqj - 2.f*dot;
    float D = sqrtf(fmaxf(d2, 1e-12f)) + 1e-6f;
    float a = 0.5f*(ai + aj);
    float p = __expf(-a * __logf(D));
    p = fminf(fmaxf(p, 1e-8f), 1000.f);
    float kvv = p * __expf(D * (-1.f/12.f));
    if (j == i) kvv = 0.f;
    vals[it] = kvv;
    lsum += kvv;
  }
#pragma unroll
  for (int off = 32; off > 0; off >>= 1) lsum += __shfl_down(lsum, off);
  __shared__ float red[4];
  if ((t & 63) == 0) red[t >> 6] = lsum;
  __syncthreads();
  const float inv = 1.f / (red[0] + red[1] + red[2] + red[3] + 1e-8f);
  const size_t rowoff = (size_t)i * NN;
#pragma unroll
  for (int it = 0; it < 24; ++it) Kout[rowoff + t + it*256] = vals[it] * inv;
}

__global__ __launch_bounds__(256) void gemm_fallback(const float* __restrict__ Afp,
                                                     const float* __restrict__ Bfp,
                                                     float* __restrict__ out) {
  __shared__ __align__(16) short As[2][128][72];
  __shared__ __align__(16) short Bs[2][64][72];
  const int t = threadIdx.x;
  const int rowBase = blockIdx.x * 128;
  const int colBase = blockIdx.y * 64;
  const int lane = t & 63;
  const int w  = t >> 6;
  const int wr = w >> 1;
  const int wc = w & 1;
  const int fr = lane & 15;
  const int fk = lane >> 4;
  int4 ra[4], rb[2];
  auto load_regs = [&](int kt) {
#pragma unroll
    for (int s = 0; s < 4; ++s) {
      int c = t + s*256; int rr = c >> 3, q = c & 7;
      const float* src = Afp + (size_t)(rowBase + rr)*NN + kt*64 + q*8;
      float4 f0 = *(const float4*)src;
      float4 f1 = *(const float4*)(src + 4);
      __hip_bfloat16 h[8];
      h[0]=__float2bfloat16(f0.x); h[1]=__float2bfloat16(f0.y);
      h[2]=__float2bfloat16(f0.z); h[3]=__float2bfloat16(f0.w);
      h[4]=__float2bfloat16(f1.x); h[5]=__float2bfloat16(f1.y);
      h[6]=__float2bfloat16(f1.z); h[7]=__float2bfloat16(f1.w);
      ra[s] = *(const int4*)h;
    }
#pragma unroll
    for (int s = 0; s < 2; ++s) {
      int c = t + s*256; int rr = c >> 3, q = c & 7;
      const float* src = Bfp + (size_t)(kt*64 + q*8)*DLAT + colBase + rr;
      __hip_bfloat16 h[8];
#pragma unroll
      for (int i2 = 0; i2 < 8; ++i2) h[i2] = __float2bfloat16(src[(size_t)i2*DLAT]);
      rb[s] = *(const int4*)h;
    }
  };
  auto write_tiles = [&](int buf) {
#pragma unroll
    for (int s = 0; s < 4; ++s) {
      int c = t + s*256; int rr = c >> 3, q = c & 7;
      *(int4*)&As[buf][rr][q*8] = ra[s];
    }
#pragma unroll
    for (int s = 0; s < 2; ++s) {
      int c = t + s*256; int rr = c >> 3, q = c & 7;
      *(int4*)&Bs[buf][rr][q*8] = rb[s];
    }
  };
  f32x4 acc[4][2];
#pragma unroll
  for (int m = 0; m < 4; ++m)
#pragma unroll
    for (int n = 0; n < 2; ++n) acc[m][n] = (f32x4){0.f,0.f,0.f,0.f};
  auto compute = [&](int buf) {
#pragma unroll
    for (int ks = 0; ks < 2; ++ks) {
      bf16x8 av[4], bv[2];
#pragma unroll
      for (int m = 0; m < 4; ++m) av[m] = *(const bf16x8*)&As[buf][wr*64 + m*16 + fr][ks*32 + fk*8];
#pragma unroll
      for (int n = 0; n < 2; ++n) bv[n] = *(const bf16x8*)&Bs[buf][wc*32 + n*16 + fr][ks*32 + fk*8];
#pragma unroll
      for (int m = 0; m < 4; ++m)
#pragma unroll
        for (int n = 0; n < 2; ++n)
          acc[m][n] = __builtin_amdgcn_mfma_f32_16x16x32_bf16(av[m], bv[n], acc[m][n], 0, 0, 0);
    }
  };
  load_regs(0); write_tiles(0); __syncthreads();
  int buf = 0;
  for (int kt = 0; kt < 96; ++kt) {
    if (kt + 1 < 96) load_regs(kt + 1);
    compute(buf);
    if (kt + 1 < 96) write_tiles(buf ^ 1);
    __syncthreads();
    buf ^= 1;
  }
#pragma unroll
  for (int m = 0; m < 4; ++m)
#pragma unroll
    for (int n = 0; n < 2; ++n) {
      const int row0 = rowBase + wr*64 + m*16 + fk*4;
      const int c0   = colBase + wc*32 + n*16 + fr;
#pragma unroll
      for (int i2 = 0; i2 < 4; ++i2)
        out[(size_t)(row0 + i2)*DLAT + c0] = acc[m][n][i2];
    }
}

extern "C" void kernel_launch(void* const* d_in, const int* in_sizes, int n_in,
                              void* d_out, int out_size, void* d_ws, size_t ws_size,
                              hipStream_t stream) {
  const float* latent = (const float*)d_in[0];
  const float* coords = (const float*)d_in[1];
  const float* alpha  = (const float*)d_in[2];
  float* out  = (float*)d_out;                       // [6144,512]
  float* Kout = out + (size_t)NN * DLAT;             // [6144,6144]

  const size_t needB = (size_t)NN * DLAT * 2;        // BT2 bf16 (6.29 MB)
  const size_t needP = (size_t)NN * 16;              // pre float4
  const size_t needI = (size_t)NN * 4;               // inv
  const size_t needS = (size_t)SPLITK * NN * DLAT * 4;  // partials (50.3 MB)

  if (ws_size >= needB + needP + needI + needS) {
    __hip_bfloat16* BT2 = (__hip_bfloat16*)d_ws;
    float4* pre  = (float4*)((char*)d_ws + needB);
    float* inv   = (float*)((char*)d_ws + needB + needP);
    float* parts = (float*)((char*)d_ws + needB + needP + needI);

    prep_kernel<<<NN/256, 256, 0, stream>>>(coords, alpha, pre);
    aux_kernel<<<NROWBLK + NN/8, 256, 0, stream>>>(latent, pre, BT2, inv);
    fused_kernel<<<NWG, 256, 0, stream>>>(pre, inv, BT2, Kout, parts);
    reduce_kernel<<<1024, 256, 0, stream>>>((const f32x4*)parts, (f32x4*)out, SPLITK);
  } else {
    buildk_kernel<<<NN, 256, 0, stream>>>(coords, alpha, Kout);
    gemm_fallback<<<dim3(NN/128, DLAT/64), 256, 0, stream>>>(Kout, latent, out);
  }
}